// Round 3
// baseline (240.508 us; speedup 1.0000x reference)
//
#include <hip/hip_runtime.h>

// Grouped rational (Pade) activation: y = P(x) / (1 + |x * q(x)|)
// B=4, L=4096, D=2048, G=8 -> dg=256 channels/group.
// Memory-bound elementwise: 268 MB ideal traffic, ~43 us @ 6.3 TB/s ceiling.
// Timed graph also contains ~160 us of harness re-poison fills (2x 512 MiB
// @ ~6.8 TB/s, observed in rocprof) -- not controllable.
//
// History:
//   R0 one-shot + IEEE div:            224.5 us
//   R1 grid-stride@2048 + NT store:    233.8 us  (regressed; confounded pair)
//   R2 one-shot + rcp:                 223.2 us  (kernel portion ~63 us = 4.3 TB/s)
// R3 (this): grid-stride@2048, PLAIN stores, explicit MLP=4 (4 float4 loads
// in flight per thread, m13 copy pattern). Tests "NT store was the R1
// regression" + attacks the 63->43 us streaming gap via per-thread ILP.

#define N_GROUPS 8

typedef float f32x4 __attribute__((ext_vector_type(4)));

__global__ __launch_bounds__(256) void rational_act_kernel(
    const float* __restrict__ x,
    const float* __restrict__ num_v,   // (G, 6)
    const float* __restrict__ den_v,   // (G, 4)
    float* __restrict__ out,
    int n4)                            // total elements / 4
{
    const int stride = gridDim.x * blockDim.x;   // host guarantees (stride>>6)%8==0
    int i = blockIdx.x * blockDim.x + threadIdx.x;

    // Thread handles flat channels [4i, 4i+4). Wave (64 lanes x float4 = 256
    // channels, wave-aligned) maps to exactly one group: g=(i>>6)&7, wave-
    // uniform. stride>>6 is a multiple of 8 (blocks even), so g is also
    // LOOP-INVARIANT: coeffs hoist out of the loop as scalar (SGPR) loads.
    const int g = __builtin_amdgcn_readfirstlane((i >> 6) & (N_GROUPS - 1));

    const float a0 = num_v[g * 6 + 0];
    const float a1 = num_v[g * 6 + 1];
    const float a2 = num_v[g * 6 + 2];
    const float a3 = num_v[g * 6 + 3];
    const float a4 = num_v[g * 6 + 4];
    const float a5 = num_v[g * 6 + 5];
    const float b0 = den_v[g * 4 + 0];
    const float b1 = den_v[g * 4 + 1];
    const float b2 = den_v[g * 4 + 2];
    const float b3 = den_v[g * 4 + 3];

    auto rat4 = [&](f32x4 xv) -> f32x4 {
        f32x4 r;
#pragma unroll
        for (int k = 0; k < 4; ++k) {
            const float xx = xv[k];
            // Horner numerator: a5*x^5 + ... + a0 (matches reference order)
            float num = fmaf(a5, xx, a4);
            num = fmaf(num, xx, a3);
            num = fmaf(num, xx, a2);
            num = fmaf(num, xx, a1);
            num = fmaf(num, xx, a0);
            // Horner q(x) = b3*x^3 + b2*x^2 + b1*x + b0
            float z = fmaf(b3, xx, b2);
            z = fmaf(z, xx, b1);
            z = fmaf(z, xx, b0);
            const float den = 1.0f + fabsf(xx * z);   // den >= 1: rcp safe
            r[k] = num * __builtin_amdgcn_rcpf(den);
        }
        return r;
    };

    const f32x4* __restrict__ xv4 = reinterpret_cast<const f32x4*>(x);
    f32x4* __restrict__ ov4       = reinterpret_cast<f32x4*>(out);

    // Main loop: batches of 4 independent float4 loads -> 4 in flight per
    // thread (MLP=4), then compute, then 4 plain stores (L2 write-combining
    // intact -- NT stores regressed in R1). For this shape n4/stride = 16:
    // each thread runs exactly 4 batches, tail never executes.
    while (i + 3 * stride < n4) {
        const f32x4 v0 = xv4[i];
        const f32x4 v1 = xv4[i + stride];
        const f32x4 v2 = xv4[i + 2 * stride];
        const f32x4 v3 = xv4[i + 3 * stride];
        const f32x4 r0 = rat4(v0);
        const f32x4 r1 = rat4(v1);
        const f32x4 r2 = rat4(v2);
        const f32x4 r3 = rat4(v3);
        ov4[i]              = r0;
        ov4[i + stride]     = r1;
        ov4[i + 2 * stride] = r2;
        ov4[i + 3 * stride] = r3;
        i += 4 * stride;
    }
    // Safety tail for shapes where n4 % (4*stride) != 0 (not taken here).
    for (; i < n4; i += stride) {
        ov4[i] = rat4(xv4[i]);
    }
}

extern "C" void kernel_launch(void* const* d_in, const int* in_sizes, int n_in,
                              void* d_out, int out_size, void* d_ws, size_t ws_size,
                              hipStream_t stream) {
    const float* x    = (const float*)d_in[0];   // (B, L, D) fp32
    const float* nv   = (const float*)d_in[1];   // (G, 6) fp32
    const float* dv   = (const float*)d_in[2];   // (G, 4) fp32
    float* out        = (float*)d_out;           // (B, L, D) fp32

    const int n = out_size;          // 4*4096*2048 = 33,554,432
    const int n4 = n / 4;            // exact (power of two)
    const int threads = 256;

    // G11 memory-bound pattern (m13: 6.29 TB/s): ~2048 blocks = 8 blocks/CU
    // = 32 waves/CU, grid-stride for the rest. Blocks even so stride>>6 is a
    // multiple of 8 (group index loop-invariant in the kernel).
    int blocks = (n4 + threads - 1) / threads;
    if (blocks > 2048) blocks = 2048;
    blocks = (blocks + 1) & ~1;

    rational_act_kernel<<<blocks, threads, 0, stream>>>(x, nv, dv, out, n4);
}

// Round 4
// 225.558 us; speedup vs baseline: 1.0663x; 1.0663x over previous
//
#include <hip/hip_runtime.h>

// Grouped rational (Pade) activation: y = P(x) / (1 + |x * q(x)|)
// B=4, L=4096, D=2048, G=8 -> dg=256 channels/group.
// Memory-bound elementwise: 268 MB ideal traffic, ~43 us @ 6.3 TB/s copy
// ceiling; measured mixed R/W efficiency tops out ~4.2 TB/s (see history).
// Timed graph also contains ~160 us of harness re-poison fills (2x 512 MiB
// @ ~6.8 TB/s, observed in rocprof) -- not controllable.
//
// History (kernel-portion times inferred from total - fills, cross-checked
// against rocprof where the kernel cracked top-5):
//   R0 one-shot + IEEE div:            224.5 total (~64 us kernel)
//   R1 grid-stride@2048 + NT store:    233.8 total (~74 us kernel)
//   R2 one-shot + rcp:                 223.2 total (~64 us kernel)  <- BEST
//   R3 grid-stride@2048 + MLP=4:       240.5 total (85.5 us kernel, MEASURED:
//        hbm 2.4 TB/s, VALUBusy 10%, Occ 52% -- concurrency abundant, BW fell)
// Conclusion: every deviation from the simple block-ordered sequential sweep
// (grid-stride, NT stores, per-thread MLP) degraded DRAM scheduling
// efficiency monotonically with concurrent stream count. One-shot one-float4-
// per-thread is the measured optimum; this file is the exact R2 revert.

#define N_GROUPS 8

__global__ __launch_bounds__(256) void rational_act_kernel(
    const float* __restrict__ x,
    const float* __restrict__ num_v,   // (G, 6)
    const float* __restrict__ den_v,   // (G, 4)
    float* __restrict__ out,
    int n4)                            // total elements / 4
{
    const int i = blockIdx.x * blockDim.x + threadIdx.x;
    if (i >= n4) return;

    // Thread i handles flat channels [4i, 4i+4). Group boundaries are at
    // multiples of 256 channels, so a wave (64 lanes x float4 = 256 channels,
    // wave-aligned since blockDim=256) maps to EXACTLY one group:
    //   g = ((4i) % 2048) / 256 = (i >> 6) & 7   -- wave-uniform.
    // readfirstlane makes that provable to the compiler -> coeffs become
    // scalar loads (SGPRs), keeping the vector memory pipe for data only.
    const int g = __builtin_amdgcn_readfirstlane((i >> 6) & (N_GROUPS - 1));

    const float a0 = num_v[g * 6 + 0];
    const float a1 = num_v[g * 6 + 1];
    const float a2 = num_v[g * 6 + 2];
    const float a3 = num_v[g * 6 + 3];
    const float a4 = num_v[g * 6 + 4];
    const float a5 = num_v[g * 6 + 5];
    const float b0 = den_v[g * 4 + 0];
    const float b1 = den_v[g * 4 + 1];
    const float b2 = den_v[g * 4 + 2];
    const float b3 = den_v[g * 4 + 3];

    const float4 xv = reinterpret_cast<const float4*>(x)[i];
    float xs[4] = {xv.x, xv.y, xv.z, xv.w};
    float rs[4];

#pragma unroll
    for (int k = 0; k < 4; ++k) {
        const float xx = xs[k];
        // Horner numerator: a5*x^5 + ... + a0 (matches reference order)
        float num = fmaf(a5, xx, a4);
        num = fmaf(num, xx, a3);
        num = fmaf(num, xx, a2);
        num = fmaf(num, xx, a1);
        num = fmaf(num, xx, a0);
        // Horner q(x) = b3*x^3 + b2*x^2 + b1*x + b0
        float z = fmaf(b3, xx, b2);
        z = fmaf(z, xx, b1);
        z = fmaf(z, xx, b0);
        const float den = 1.0f + fabsf(xx * z);   // den >= 1: rcp is safe
        rs[k] = num * __builtin_amdgcn_rcpf(den);
    }

    float4 r;
    r.x = rs[0]; r.y = rs[1]; r.z = rs[2]; r.w = rs[3];
    reinterpret_cast<float4*>(out)[i] = r;
}

extern "C" void kernel_launch(void* const* d_in, const int* in_sizes, int n_in,
                              void* d_out, int out_size, void* d_ws, size_t ws_size,
                              hipStream_t stream) {
    const float* x    = (const float*)d_in[0];   // (B, L, D) fp32
    const float* nv   = (const float*)d_in[1];   // (G, 6) fp32
    const float* dv   = (const float*)d_in[2];   // (G, 4) fp32
    float* out        = (float*)d_out;           // (B, L, D) fp32

    const int n = out_size;          // 4*4096*2048 = 33,554,432
    const int n4 = n / 4;            // exact (power of two)
    const int threads = 256;
    const int blocks = (n4 + threads - 1) / threads;

    rational_act_kernel<<<blocks, threads, 0, stream>>>(x, nv, dv, out, n4);
}